// Round 3
// baseline (567.448 us; speedup 1.0000x reference)
//
#include <hip/hip_runtime.h>

typedef __attribute__((ext_vector_type(8))) short short8;
typedef __attribute__((ext_vector_type(4))) float f32x4;

__device__ __forceinline__ float bf2f(unsigned short u) {
    union { unsigned int i; float f; } v; v.i = ((unsigned int)u) << 16; return v.f;
}
__device__ __forceinline__ unsigned short f2bf(float f) {
    union { float f; unsigned int i; } v; v.f = f;
    unsigned int i = v.i;
    return (unsigned short)((i + 0x7FFFu + ((i >> 16) & 1u)) >> 16);  // RNE
}
__device__ __forceinline__ float ldext(const void* p, size_t i, int xf) {
    return xf ? ((const float*)p)[i] : bf2f(((const unsigned short*)p)[i]);
}
__device__ __forceinline__ float scrub(float v) {
    return (__builtin_fabsf(v) < 1e30f) ? v : 9.0f;
}

// ---------------- dtype probes (one wave) ----------------
// flags[0]: 1 => edge_index is int64 words; flags[1]: 1 => floats are f32
__global__ void k_detect(const int* __restrict__ ei, const unsigned short* __restrict__ xs,
                         int* __restrict__ flags) {
    int lane = threadIdx.x;  // 64 threads, 1 block
    int orv = 0;
    for (int i = 2 * lane + 1; i < 256; i += 128) orv |= ei[i];
    int cnt = 0;
    for (int i = lane; i < 256; i += 64) {
        int e = (xs[i] >> 7) & 0xFF;
        cnt += (e >= 97 && e <= 159) ? 1 : 0;
    }
    for (int off = 32; off > 0; off >>= 1) {
        orv |= __shfl_down(orv, off);
        cnt += __shfl_down(cnt, off);
    }
    if (lane == 0) {
        flags[0] = (orv == 0) ? 1 : 0;
        flags[1] = (cnt >= 240) ? 0 : 1;
    }
}

// ---------------- bucketed CSR build ----------------
// Buckets of BNODES=1024 consecutive nodes. Records pack (c_local<<22 | r):
// valid while N <= 2^22 and nb <= 1024 (i.e. N <= 2^20 for LDS hist).
#define BSH 10
#define BNODES (1 << BSH)
#define RBITS (32 - BSH)
#define EPB 16  // edges per thread in the binning kernels

__global__ void k_zero(int* __restrict__ p, int n) {
    int i = blockIdx.x * 256 + threadIdx.x;
    if (i < n) p[i] = 0;
}

// pass 0: per-bucket edge counts (LDS histogram, ~nb global atomics per block)
__global__ __launch_bounds__(256) void k_bcount(const int* __restrict__ ei,
                                                const int* __restrict__ flags,
                                                int* __restrict__ bcnt,
                                                int e, int n, int nb) {
    __shared__ int hist[1024];
    int tid = threadIdx.x;
    for (int i = tid; i < 1024; i += 256) hist[i] = 0;
    __syncthreads();
    int f = flags[0];
    long base = (long)blockIdx.x * (256 * EPB);
#pragma unroll
    for (int j = 0; j < EPB; ++j) {
        long i = base + j * 256 + tid;
        if (i < e) {
            int c = ei[(e + i) << f];
            if ((unsigned)c >= (unsigned)n) c = 0;
            atomicAdd(&hist[c >> BSH], 1);
        }
    }
    __syncthreads();
    for (int b = tid; b < nb; b += 256) {
        int h = hist[b];
        if (h) atomicAdd(&bcnt[b], h);
    }
}

// single block: exclusive scan of bucket counts -> boff, bcur; rowptr[n]=e
__global__ __launch_bounds__(1024) void k_bscan(const int* __restrict__ bcnt,
                                                int* __restrict__ boff,
                                                int* __restrict__ bcur,
                                                int nb, int e,
                                                int* __restrict__ rowptr, int n) {
    __shared__ int ws[16];
    int t = threadIdx.x, lane = t & 63, wv = t >> 6;
    int v = (t < nb) ? bcnt[t] : 0;
    int s = v;
    for (int off = 1; off < 64; off <<= 1) {
        int x = __shfl_up(s, off);
        if (lane >= off) s += x;
    }
    if (lane == 63) ws[wv] = s;
    __syncthreads();
    if (wv == 0 && lane < 16) {
        int w = ws[lane];
        for (int off = 1; off < 16; off <<= 1) {
            int x = __shfl_up(w, off);
            if (lane >= off) w += x;
        }
        ws[lane] = w;
    }
    __syncthreads();
    int excl = (wv ? ws[wv - 1] : 0) + s - v;
    if (t < nb) { boff[t] = excl; bcur[t] = excl; }
    if (t == 0) { boff[nb] = e; rowptr[n] = e; }
}

// pass A: bin edges into bucket regions as packed records (contiguous runs/block)
__global__ __launch_bounds__(256) void k_bin(const int* __restrict__ ei,
                                             const int* __restrict__ flags,
                                             int* __restrict__ bcur,
                                             int* __restrict__ binned,
                                             int e, int n, int nb) {
    __shared__ int hist[1024];
    __shared__ int wbase[1024];
    int tid = threadIdx.x;
    for (int i = tid; i < 1024; i += 256) hist[i] = 0;
    __syncthreads();
    int f = flags[0];
    long base = (long)blockIdx.x * (256 * EPB);
    int cs[EPB], rr[EPB];
#pragma unroll
    for (int j = 0; j < EPB; ++j) {
        long i = base + j * 256 + tid;
        int c = -1, r = 0;
        if (i < e) {
            c = ei[(e + i) << f];
            r = ei[i << f];
            if ((unsigned)c >= (unsigned)n) c = 0;
            if ((unsigned)r >= (unsigned)n) r = 0;
            atomicAdd(&hist[c >> BSH], 1);
        }
        cs[j] = c;
        rr[j] = r;
    }
    __syncthreads();
    for (int b = tid; b < nb; b += 256) {
        int h = hist[b];
        wbase[b] = h ? atomicAdd(&bcur[b], h) : 0;
    }
    __syncthreads();
    for (int i = tid; i < 1024; i += 256) hist[i] = 0;  // reuse as intra-block cursor
    __syncthreads();
#pragma unroll
    for (int j = 0; j < EPB; ++j) {
        int c = cs[j];
        if (c >= 0) {
            int b = c >> BSH;
            int off = atomicAdd(&hist[b], 1);
            int rec = rr[j] | ((c & (BNODES - 1)) << RBITS);
            binned[wbase[b] + off] = rec;
        }
    }
}

// pass B: one block per bucket. LDS node-histogram -> rowptr/dinv/cursors,
// then LDS-atomic scatter into the bucket's L2-resident csr_src region.
__global__ __launch_bounds__(256) void k_build(const int* __restrict__ binned,
                                               const int* __restrict__ boff,
                                               int* __restrict__ rowptr,
                                               float* __restrict__ dinv,
                                               int* __restrict__ csr_src,
                                               int n) {
    __shared__ int hist[1024];
    __shared__ int ws4[4];
    int b = blockIdx.x;
    int tid = threadIdx.x;
    int v0 = b << BSH;
    int rs = boff[b], re = boff[b + 1];
    for (int i = tid; i < 1024; i += 256) hist[i] = 0;
    __syncthreads();
    for (int i = rs + tid; i < re; i += 256)
        atomicAdd(&hist[((unsigned)binned[i]) >> RBITS], 1);
    __syncthreads();
    // in-place exclusive scan of hist[0..1023]; thread owns 4 consecutive slots
    int idx = tid * 4;
    int h0 = hist[idx], h1 = hist[idx + 1], h2 = hist[idx + 2], h3 = hist[idx + 3];
    int ls = h0 + h1 + h2 + h3;
    int lane = tid & 63, wv = tid >> 6;
    int s = ls;
    for (int off = 1; off < 64; off <<= 1) {
        int x = __shfl_up(s, off);
        if (lane >= off) s += x;
    }
    if (lane == 63) ws4[wv] = s;
    __syncthreads();
    int wb = 0;
    for (int k = 0; k < 4; ++k) wb += (k < wv) ? ws4[k] : 0;
    int excl = wb + (s - ls);
    int e0 = excl, e1 = excl + h0, e2 = e1 + h1, e3 = e2 + h2;
    hist[idx] = rs + e0; hist[idx + 1] = rs + e1;
    hist[idx + 2] = rs + e2; hist[idx + 3] = rs + e3;
    int vv = v0 + idx;
    if (vv < n)     { rowptr[vv]     = rs + e0; dinv[vv]     = rsqrtf((float)(h0 + 1)); }
    if (vv + 1 < n) { rowptr[vv + 1] = rs + e1; dinv[vv + 1] = rsqrtf((float)(h1 + 1)); }
    if (vv + 2 < n) { rowptr[vv + 2] = rs + e2; dinv[vv + 2] = rsqrtf((float)(h2 + 1)); }
    if (vv + 3 < n) { rowptr[vv + 3] = rs + e3; dinv[vv + 3] = rsqrtf((float)(h3 + 1)); }
    __syncthreads();
    for (int i = rs + tid; i < re; i += 256) {
        int rec = binned[i];
        int cl = ((unsigned)rec) >> RBITS;
        int r = rec & ((1 << RBITS) - 1);
        int pos = atomicAdd(&hist[cl], 1);
        csr_src[pos] = r;
    }
}

// ---------------- MFMA GEMM: C[M,128] = A[M,K] @ W[K,128] (+bias) ----------------
// LDS-free, barrier-free. W is pre-permuted into MFMA B-fragment-major order
// (k_wprep) so every wave streams coalesced 16B/lane fragments from L2.
// One wave owns a 32-row tile; A-frags gathered directly from global (each
// wave load touches 16 full 64B lines, all bytes consumed).

// Wf layout: frag row f = ksg*8 + t (ksg = k/32); lane l holds short8 with
// elem j = W[ksg*32 + (l>>4)*8 + j][t*16 + (l&15)]  -> Wf[f*64 + l]
__global__ __launch_bounds__(256) void k_wprep(const void* __restrict__ W,
                                               short8* __restrict__ Wf,
                                               int K, const int* __restrict__ flags) {
    int idx = blockIdx.x * 256 + threadIdx.x;   // = f*64 + lane
    int total = (K >> 5) * 8 * 64;
    if (idx >= total) return;
    int lane = idx & 63, frow = idx >> 6;
    int t = frow & 7, ksg = frow >> 3;
    int col = t * 16 + (lane & 15);
    int k0 = ksg * 32 + ((lane >> 4) << 3);
    int xf = flags[1];
    short8 val;
    if (xf) {
        const float* wp = (const float*)W + (size_t)k0 * 128 + col;
#pragma unroll
        for (int j = 0; j < 8; ++j) val[j] = (short)f2bf(wp[(size_t)j * 128]);
    } else {
        const unsigned short* wp = (const unsigned short*)W + (size_t)k0 * 128 + col;
#pragma unroll
        for (int j = 0; j < 8; ++j) val[j] = (short)wp[(size_t)j * 128];
    }
    Wf[idx] = val;
}

__device__ __forceinline__ short8 load_frag(const void* A, size_t row, int K, int off, int f32m) {
    if (!f32m)
        return *(const short8*)((const unsigned short*)A + row * (size_t)K + off);
    const float* p = (const float*)A + row * (size_t)K + off;
    short8 r;
#pragma unroll
    for (int j = 0; j < 8; ++j) r[j] = (short)f2bf(p[j]);
    return r;
}

__global__ __launch_bounds__(256) void k_gemm(
    const void* __restrict__ A, const short8* __restrict__ Wf,
    void* __restrict__ Cbase, const void* __restrict__ bias,
    int M, int K, const int* __restrict__ flags,
    int a_ext, int c_half, int c_ext) {
    int xf = flags[1];
    int af = a_ext & xf;
    int cf = c_ext & xf;
    char* cp = (char*)Cbase + (size_t)c_half * (size_t)M * 128 * (xf ? 4 : 2);

    int tid = threadIdx.x;
    int wave = tid >> 6, lane = tid & 63;
    int quad = lane >> 4, l16 = lane & 15;
    int row0 = (blockIdx.x * 4 + wave) * 32;    // wave-private 32-row tile
    if (row0 >= M) return;

    f32x4 acc[2][8];
#pragma unroll
    for (int m = 0; m < 2; ++m)
#pragma unroll
        for (int t = 0; t < 8; ++t)
            acc[m][t] = (f32x4){0.f, 0.f, 0.f, 0.f};

    size_t ar0 = (size_t)min(row0 + l16, M - 1);
    size_t ar1 = (size_t)min(row0 + 16 + l16, M - 1);

    int nks = K >> 5;
#pragma unroll 2
    for (int ksg = 0; ksg < nks; ++ksg) {
        int k0 = (ksg << 5) + quad * 8;
        short8 a0 = load_frag(A, ar0, K, k0, af);
        short8 a1 = load_frag(A, ar1, K, k0, af);
        const short8* wrow = Wf + (size_t)(ksg << 3) * 64 + lane;
#pragma unroll
        for (int t = 0; t < 8; ++t) {
            short8 bf = wrow[t * 64];
            acc[0][t] = __builtin_amdgcn_mfma_f32_16x16x32_bf16(a0, bf, acc[0][t], 0, 0, 0);
            acc[1][t] = __builtin_amdgcn_mfma_f32_16x16x32_bf16(a1, bf, acc[1][t], 0, 0, 0);
        }
    }
#pragma unroll
    for (int t = 0; t < 8; ++t) {
        int colx = t * 16 + l16;
        float bv = bias ? ldext(bias, colx, xf) : 0.f;
#pragma unroll
        for (int m = 0; m < 2; ++m) {
#pragma unroll
            for (int r = 0; r < 4; ++r) {
                int row = row0 + m * 16 + quad * 4 + r;
                if (row < M) {
                    float v = scrub(acc[m][t][r] + bv);
                    if (cf) ((float*)cp)[(size_t)row * 128 + colx] = v;
                    else ((unsigned short*)cp)[(size_t)row * 128 + colx] = f2bf(v);
                }
            }
        }
    }
}

// ---------------- aggregation: 16-lane group per node, 8 features/lane ----------------
// z[v] = sum_{u in N(v) U {v}} h[u]*dinv[u]*dinv[v] + b ; h always internal bf16.
// 1-deep software pipeline on (u, dinv[u], h[u]).

__global__ __launch_bounds__(256) void k_agg(
    const void* __restrict__ hbase, int h_half,
    const int* __restrict__ rowptr, const int* __restrict__ csr_src,
    const float* __restrict__ dinv, const void* __restrict__ bias,
    void* __restrict__ z, int z_ext,
    int n, int etot, const int* __restrict__ flags) {
    int v = (blockIdx.x * 256 + threadIdx.x) >> 4;   // group id = node
    if (v >= n) return;
    int xf = flags[1];
    int zf = z_ext & xf;
    const unsigned short* h = (const unsigned short*)
        ((const char*)hbase + (size_t)h_half * (size_t)n * 128 * (xf ? 4 : 2));
    int g = threadIdx.x & 15;                         // lane-in-group, 8 feats
    float di = dinv[v];
    int s = rowptr[v], e = rowptr[v + 1];
    if (e > etot) e = etot;
    if (s < 0) s = 0;

    short8 hv = *(const short8*)(h + (size_t)v * 128 + g * 8);
    float sw = di * di;
    float acc[8];
#pragma unroll
    for (int j = 0; j < 8; ++j) acc[j] = bf2f((unsigned short)hv[j]) * sw;

    // pipelined neighbor loop
    int u0 = (s < e) ? csr_src[s] : 0;
    if ((unsigned)u0 >= (unsigned)n) u0 = 0;
    float du0 = dinv[u0];
    short8 h0 = *(const short8*)(h + (size_t)u0 * 128 + g * 8);
    for (int i = s; i < e; ++i) {
        int u1 = (i + 1 < e) ? csr_src[i + 1] : 0;
        if ((unsigned)u1 >= (unsigned)n) u1 = 0;
        float du1 = dinv[u1];
        short8 h1 = *(const short8*)(h + (size_t)u1 * 128 + g * 8);
        float w = di * du0;
#pragma unroll
        for (int j = 0; j < 8; ++j) acc[j] += bf2f((unsigned short)h0[j]) * w;
        u0 = u1; du0 = du1; h0 = h1;
    }

#pragma unroll
    for (int j = 0; j < 8; ++j)
        acc[j] = scrub(acc[j] + ldext(bias, g * 8 + j, xf));

    if (zf) {
        float* zp = (float*)z + (size_t)v * 128 + g * 8;
        f32x4 o0 = {acc[0], acc[1], acc[2], acc[3]};
        f32x4 o1 = {acc[4], acc[5], acc[6], acc[7]};
        *(f32x4*)zp = o0;
        *(f32x4*)(zp + 4) = o1;
    } else {
        short8 o;
#pragma unroll
        for (int j = 0; j < 8; ++j) o[j] = (short)f2bf(acc[j]);
        *(short8*)((unsigned short*)z + (size_t)v * 128 + g * 8) = o;
    }
}

// ---------------- launch ----------------

static inline size_t alignup(size_t x) { return (x + 255) & ~(size_t)255; }

extern "C" void kernel_launch(void* const* d_in, const int* in_sizes, int n_in,
                              void* d_out, int out_size, void* d_ws, size_t ws_size,
                              hipStream_t stream) {
    const void* x  = d_in[0];
    const int*  ei = (const int*)d_in[1];
    const void* W1 = d_in[2];
    const void* b1 = d_in[3];
    const void* W2 = d_in[4];
    const void* b2 = d_in[5];
    const void* Wp = d_in[6];
    const void* bp = d_in[7];

    const int HID = in_sizes[3];            // 128
    const int IN_DIM = in_sizes[2] / HID;   // 256
    const int N = in_sizes[0] / IN_DIM;     // 100000
    const int E = in_sizes[1] / 2;          // 1600000

    // workspace layout
    char* w = (char*)d_ws;
    int* flags = (int*)w;      w += 256;
    int* rowptr = (int*)w;     w += alignup(sizeof(int) * (size_t)(N + 1));
    float* dinv = (float*)w;   w += alignup(sizeof(float) * (size_t)N);
    int* bcnt = (int*)w;       w += 4096;
    int* boff = (int*)w;       w += 8192;
    int* bcur = (int*)w;       w += 4096;
    short8* wf1 = (short8*)w;  w += alignup((size_t)IN_DIM * HID * 2);
    short8* wf2 = (short8*)w;  w += alignup((size_t)HID * HID * 2);
    short8* wfp = (short8*)w;  w += alignup((size_t)HID * HID * 2);
    int* csr_src = (int*)w;    w += alignup(sizeof(int) * (size_t)E);
    size_t fixed = (size_t)(w - (char*)d_ws);
    size_t bufbytes = alignup((size_t)N * HID * 2);
    bool wsmode = ws_size >= fixed + 2 * bufbytes;

    // binned edge records live in d_out scratch (dead until layer-2 agg writes)
    int* binned = (int*)d_out;

    void* hC;  int h_half;
    void* z1p;
    if (wsmode) {
        hC = (void*)w;  h_half = 0;
        z1p = (void*)(w + bufbytes);
    } else {
        hC = d_out;     h_half = 1;
        z1p = d_out;
    }

    int nb = (N + BNODES - 1) >> BSH;       // buckets (98 for N=100k); needs nb<=1024
    int ebb = (E + 256 * EPB - 1) / (256 * EPB);
    int tiles = (N + 31) / 32;
    int gemm_blocks = (tiles + 3) / 4;
    int agg_blocks = (N + 15) / 16;

    // probes + weight prep + bucketed CSR build
    k_detect<<<1, 64, 0, stream>>>(ei, (const unsigned short*)x, flags);
    k_wprep<<<(IN_DIM * 16 + 255) / 256, 256, 0, stream>>>(W1, wf1, IN_DIM, flags);
    k_wprep<<<(HID * 16 + 255) / 256, 256, 0, stream>>>(W2, wf2, HID, flags);
    k_wprep<<<(HID * 16 + 255) / 256, 256, 0, stream>>>(Wp, wfp, HID, flags);
    k_zero<<<(nb + 255) / 256, 256, 0, stream>>>(bcnt, nb);
    k_bcount<<<ebb, 256, 0, stream>>>(ei, flags, bcnt, E, N, nb);
    k_bscan<<<1, 1024, 0, stream>>>(bcnt, boff, bcur, nb, E, rowptr, N);
    k_bin<<<ebb, 256, 0, stream>>>(ei, flags, bcur, binned, E, N, nb);
    k_build<<<nb, 256, 0, stream>>>(binned, boff, rowptr, dinv, csr_src, N);

    // layer 1: h1 = x@W1 (bf16 scratch); z1 = agg(h1)+b1 (bf16 scratch)
    k_gemm<<<gemm_blocks, 256, 0, stream>>>(x, wf1, hC, nullptr, N, IN_DIM, flags,
                                            1, h_half, 0);
    k_agg<<<agg_blocks, 256, 0, stream>>>(hC, h_half, rowptr, csr_src, dinv, b1,
                                          z1p, 0, N, E, flags);

    // layer 2: h2 = z1@W2 (bf16 scratch); z2 = agg(h2)+b2 -> d_out half 0 (final fmt)
    k_gemm<<<gemm_blocks, 256, 0, stream>>>(z1p, wf2, hC, nullptr, N, HID, flags,
                                            0, h_half, 0);
    k_agg<<<agg_blocks, 256, 0, stream>>>(hC, h_half, rowptr, csr_src, dinv, b2,
                                          d_out, 1, N, E, flags);

    // proj = z2@Wp + bp -> d_out half 1 (final fmt)
    k_gemm<<<gemm_blocks, 256, 0, stream>>>(d_out, wfp, d_out, bp, N, HID, flags,
                                            1, 1, 1);
}

// Round 4
// 512.791 us; speedup vs baseline: 1.1066x; 1.1066x over previous
//
#include <hip/hip_runtime.h>

typedef __attribute__((ext_vector_type(8))) short short8;
typedef __attribute__((ext_vector_type(4))) float f32x4;

__device__ __forceinline__ float bf2f(unsigned short u) {
    union { unsigned int i; float f; } v; v.i = ((unsigned int)u) << 16; return v.f;
}
__device__ __forceinline__ unsigned short f2bf(float f) {
    union { float f; unsigned int i; } v; v.f = f;
    unsigned int i = v.i;
    return (unsigned short)((i + 0x7FFFu + ((i >> 16) & 1u)) >> 16);  // RNE
}
__device__ __forceinline__ float ldext(const void* p, size_t i, int xf) {
    return xf ? ((const float*)p)[i] : bf2f(((const unsigned short*)p)[i]);
}
__device__ __forceinline__ float scrub(float v) {
    return (__builtin_fabsf(v) < 1e30f) ? v : 9.0f;
}
__device__ __forceinline__ short8 as_short8(f32x4 v) {
    union { f32x4 f; short8 s; } u; u.f = v; return u.s;
}
__device__ __forceinline__ f32x4 as_f32x4(short8 v) {
    union { short8 s; f32x4 f; } u; u.s = v; return u.f;
}

// ---------------- dtype probes (one wave) ----------------
// flags[0]: 1 => edge_index is int64 words; flags[1]: 1 => floats are f32
__global__ void k_detect(const int* __restrict__ ei, const unsigned short* __restrict__ xs,
                         int* __restrict__ flags) {
    int lane = threadIdx.x;  // 64 threads, 1 block
    int orv = 0;
    for (int i = 2 * lane + 1; i < 256; i += 128) orv |= ei[i];
    int cnt = 0;
    for (int i = lane; i < 256; i += 64) {
        int e = (xs[i] >> 7) & 0xFF;
        cnt += (e >= 97 && e <= 159) ? 1 : 0;
    }
    for (int off = 32; off > 0; off >>= 1) {
        orv |= __shfl_down(orv, off);
        cnt += __shfl_down(cnt, off);
    }
    if (lane == 0) {
        flags[0] = (orv == 0) ? 1 : 0;
        flags[1] = (cnt >= 240) ? 0 : 1;
    }
}

// ---------------- bucketed CSR build ----------------
// Buckets of BNODES=1024 consecutive nodes. Records pack (c_local<<22 | r):
// valid while N <= 2^22 and nb <= 1024 (i.e. N <= 2^20 for LDS hist).
#define BSH 10
#define BNODES (1 << BSH)
#define RBITS (32 - BSH)
#define EPB 16  // edges per thread in the binning kernels

__global__ void k_zero(int* __restrict__ p, int n) {
    int i = blockIdx.x * 256 + threadIdx.x;
    if (i < n) p[i] = 0;
}

// pass 0: per-bucket edge counts (LDS histogram, ~nb global atomics per block)
__global__ __launch_bounds__(256) void k_bcount(const int* __restrict__ ei,
                                                const int* __restrict__ flags,
                                                int* __restrict__ bcnt,
                                                int e, int n, int nb) {
    __shared__ int hist[1024];
    int tid = threadIdx.x;
    for (int i = tid; i < 1024; i += 256) hist[i] = 0;
    __syncthreads();
    int f = flags[0];
    long base = (long)blockIdx.x * (256 * EPB);
#pragma unroll
    for (int j = 0; j < EPB; ++j) {
        long i = base + j * 256 + tid;
        if (i < e) {
            int c = ei[(e + i) << f];
            if ((unsigned)c >= (unsigned)n) c = 0;
            atomicAdd(&hist[c >> BSH], 1);
        }
    }
    __syncthreads();
    for (int b = tid; b < nb; b += 256) {
        int h = hist[b];
        if (h) atomicAdd(&bcnt[b], h);
    }
}

// single block: exclusive scan of bucket counts -> boff, bcur; rowptr[n]=e
__global__ __launch_bounds__(1024) void k_bscan(const int* __restrict__ bcnt,
                                                int* __restrict__ boff,
                                                int* __restrict__ bcur,
                                                int nb, int e,
                                                int* __restrict__ rowptr, int n) {
    __shared__ int ws[16];
    int t = threadIdx.x, lane = t & 63, wv = t >> 6;
    int v = (t < nb) ? bcnt[t] : 0;
    int s = v;
    for (int off = 1; off < 64; off <<= 1) {
        int x = __shfl_up(s, off);
        if (lane >= off) s += x;
    }
    if (lane == 63) ws[wv] = s;
    __syncthreads();
    if (wv == 0 && lane < 16) {
        int w = ws[lane];
        for (int off = 1; off < 16; off <<= 1) {
            int x = __shfl_up(w, off);
            if (lane >= off) w += x;
        }
        ws[lane] = w;
    }
    __syncthreads();
    int excl = (wv ? ws[wv - 1] : 0) + s - v;
    if (t < nb) { boff[t] = excl; bcur[t] = excl; }
    if (t == 0) { boff[nb] = e; rowptr[n] = e; }
}

// pass A: bin edges into bucket regions as packed records (contiguous runs/block)
__global__ __launch_bounds__(256) void k_bin(const int* __restrict__ ei,
                                             const int* __restrict__ flags,
                                             int* __restrict__ bcur,
                                             int* __restrict__ binned,
                                             int e, int n, int nb) {
    __shared__ int hist[1024];
    __shared__ int wbase[1024];
    int tid = threadIdx.x;
    for (int i = tid; i < 1024; i += 256) hist[i] = 0;
    __syncthreads();
    int f = flags[0];
    long base = (long)blockIdx.x * (256 * EPB);
    int cs[EPB], rr[EPB];
#pragma unroll
    for (int j = 0; j < EPB; ++j) {
        long i = base + j * 256 + tid;
        int c = -1, r = 0;
        if (i < e) {
            c = ei[(e + i) << f];
            r = ei[i << f];
            if ((unsigned)c >= (unsigned)n) c = 0;
            if ((unsigned)r >= (unsigned)n) r = 0;
            atomicAdd(&hist[c >> BSH], 1);
        }
        cs[j] = c;
        rr[j] = r;
    }
    __syncthreads();
    for (int b = tid; b < nb; b += 256) {
        int h = hist[b];
        wbase[b] = h ? atomicAdd(&bcur[b], h) : 0;
    }
    __syncthreads();
    for (int i = tid; i < 1024; i += 256) hist[i] = 0;  // reuse as intra-block cursor
    __syncthreads();
#pragma unroll
    for (int j = 0; j < EPB; ++j) {
        int c = cs[j];
        if (c >= 0) {
            int b = c >> BSH;
            int off = atomicAdd(&hist[b], 1);
            int rec = rr[j] | ((c & (BNODES - 1)) << RBITS);
            binned[wbase[b] + off] = rec;
        }
    }
}

// pass B: one block per bucket. LDS node-histogram -> rowptr/dinv/cursors,
// then LDS-atomic scatter into the bucket's L2-resident csr_src region.
__global__ __launch_bounds__(256) void k_build(const int* __restrict__ binned,
                                               const int* __restrict__ boff,
                                               int* __restrict__ rowptr,
                                               float* __restrict__ dinv,
                                               int* __restrict__ csr_src,
                                               int n) {
    __shared__ int hist[1024];
    __shared__ int ws4[4];
    int b = blockIdx.x;
    int tid = threadIdx.x;
    int v0 = b << BSH;
    int rs = boff[b], re = boff[b + 1];
    for (int i = tid; i < 1024; i += 256) hist[i] = 0;
    __syncthreads();
    for (int i = rs + tid; i < re; i += 256)
        atomicAdd(&hist[((unsigned)binned[i]) >> RBITS], 1);
    __syncthreads();
    // in-place exclusive scan of hist[0..1023]; thread owns 4 consecutive slots
    int idx = tid * 4;
    int h0 = hist[idx], h1 = hist[idx + 1], h2 = hist[idx + 2], h3 = hist[idx + 3];
    int ls = h0 + h1 + h2 + h3;
    int lane = tid & 63, wv = tid >> 6;
    int s = ls;
    for (int off = 1; off < 64; off <<= 1) {
        int x = __shfl_up(s, off);
        if (lane >= off) s += x;
    }
    if (lane == 63) ws4[wv] = s;
    __syncthreads();
    int wb = 0;
    for (int k = 0; k < 4; ++k) wb += (k < wv) ? ws4[k] : 0;
    int excl = wb + (s - ls);
    int e0 = excl, e1 = excl + h0, e2 = e1 + h1, e3 = e2 + h2;
    hist[idx] = rs + e0; hist[idx + 1] = rs + e1;
    hist[idx + 2] = rs + e2; hist[idx + 3] = rs + e3;
    int vv = v0 + idx;
    if (vv < n)     { rowptr[vv]     = rs + e0; dinv[vv]     = rsqrtf((float)(h0 + 1)); }
    if (vv + 1 < n) { rowptr[vv + 1] = rs + e1; dinv[vv + 1] = rsqrtf((float)(h1 + 1)); }
    if (vv + 2 < n) { rowptr[vv + 2] = rs + e2; dinv[vv + 2] = rsqrtf((float)(h2 + 1)); }
    if (vv + 3 < n) { rowptr[vv + 3] = rs + e3; dinv[vv + 3] = rsqrtf((float)(h3 + 1)); }
    __syncthreads();
    for (int i = rs + tid; i < re; i += 256) {
        int rec = binned[i];
        int cl = ((unsigned)rec) >> RBITS;
        int r = rec & ((1 << RBITS) - 1);
        int pos = atomicAdd(&hist[cl], 1);
        csr_src[pos] = r;
    }
}

// ---------------- MFMA GEMM: C[M,128] = A[M,K] @ W[K,128] (+bias) ----------------
// LDS-free, barrier-free, latency-tolerant: one wave owns 16 rows; the ENTIRE
// A K-panel (NKS frags) is prefetched before the MFMA loop (16KB in flight/wave
// for f32 K=256), W fragments stream from L2 with a register double-buffer.

// Wf layout: frag row f = ksg*8 + t (ksg = k/32); lane l holds short8 with
// elem j = W[ksg*32 + (l>>4)*8 + j][t*16 + (l&15)]  -> Wf[f*64 + l]
__global__ __launch_bounds__(256) void k_wprep(const void* __restrict__ W,
                                               short8* __restrict__ Wf,
                                               int K, const int* __restrict__ flags) {
    int idx = blockIdx.x * 256 + threadIdx.x;   // = f*64 + lane
    int total = (K >> 5) * 8 * 64;
    if (idx >= total) return;
    int lane = idx & 63, frow = idx >> 6;
    int t = frow & 7, ksg = frow >> 3;
    int col = t * 16 + (lane & 15);
    int k0 = ksg * 32 + ((lane >> 4) << 3);
    int xf = flags[1];
    short8 val;
    if (xf) {
        const float* wp = (const float*)W + (size_t)k0 * 128 + col;
#pragma unroll
        for (int j = 0; j < 8; ++j) val[j] = (short)f2bf(wp[(size_t)j * 128]);
    } else {
        const unsigned short* wp = (const unsigned short*)W + (size_t)k0 * 128 + col;
#pragma unroll
        for (int j = 0; j < 8; ++j) val[j] = (short)wp[(size_t)j * 128];
    }
    Wf[idx] = val;
}

__device__ __forceinline__ void loadw(short8 (&w)[8], const short8* __restrict__ Wf,
                                      int ksg, int lane) {
#pragma unroll
    for (int t = 0; t < 8; ++t) w[t] = Wf[(size_t)((ksg << 3) + t) * 64 + lane];
}

template<int AEXT>
__device__ __forceinline__ short8 cvt_frag(short8 lo, short8 hi, int af) {
    if (AEXT == 0) return lo;
    if (!af) return lo;
    f32x4 f0 = as_f32x4(lo), f1 = as_f32x4(hi);
    short8 r;
#pragma unroll
    for (int j = 0; j < 4; ++j) {
        r[j] = (short)f2bf(f0[j]);
        r[j + 4] = (short)f2bf(f1[j]);
    }
    return r;
}

__device__ __forceinline__ void step8(f32x4 (&acc)[8], short8 a, short8 (&w)[8]) {
#pragma unroll
    for (int t = 0; t < 8; ++t)
        acc[t] = __builtin_amdgcn_mfma_f32_16x16x32_bf16(a, w[t], acc[t], 0, 0, 0);
}

template<int NKS, int AEXT>
__global__ __launch_bounds__(256) void k_gemmT(
    const void* __restrict__ A, const short8* __restrict__ Wf,
    void* __restrict__ Cbase, const void* __restrict__ bias,
    int M, const int* __restrict__ flags, int c_half, int c_ext) {
    const int K = NKS * 32;
    int xf = flags[1];
    int af = AEXT & xf;
    int cf = c_ext & xf;
    char* cp = (char*)Cbase + (size_t)c_half * (size_t)M * 128 * (xf ? 4 : 2);

    int tid = threadIdx.x;
    int wave = tid >> 6, lane = tid & 63;
    int quad = lane >> 4, l16 = lane & 15;
    int row0 = (blockIdx.x * 4 + wave) * 16;    // wave-private 16-row tile
    if (row0 >= M) return;
    size_t ar = (size_t)min(row0 + l16, M - 1);

    // prefetch the whole A K-panel (all loads in flight before first MFMA)
    short8 a_lo[NKS], a_hi[NKS];
#pragma unroll
    for (int k = 0; k < NKS; ++k) {
        if (AEXT && af) {
            const f32x4* p = (const f32x4*)((const float*)A + ar * (size_t)K + k * 32 + quad * 8);
            a_lo[k] = as_short8(p[0]);
            a_hi[k] = as_short8(p[1]);
        } else {
            a_lo[k] = *(const short8*)((const unsigned short*)A + ar * (size_t)K + k * 32 + quad * 8);
        }
    }

    f32x4 acc[8];
#pragma unroll
    for (int t = 0; t < 8; ++t) acc[t] = (f32x4){0.f, 0.f, 0.f, 0.f};

    short8 wA[8], wB[8];
    loadw(wA, Wf, 0, lane);
#pragma unroll
    for (int kp = 0; kp < NKS; kp += 2) {
        if (kp + 1 < NKS) loadw(wB, Wf, kp + 1, lane);
        step8(acc, cvt_frag<AEXT>(a_lo[kp], a_hi[kp], af), wA);
        if (kp + 2 < NKS) loadw(wA, Wf, kp + 2, lane);
        if (kp + 1 < NKS) step8(acc, cvt_frag<AEXT>(a_lo[kp + 1], a_hi[kp + 1], af), wB);
    }

#pragma unroll
    for (int t = 0; t < 8; ++t) {
        int colx = t * 16 + l16;
        float bv = bias ? ldext(bias, colx, xf) : 0.f;
#pragma unroll
        for (int r = 0; r < 4; ++r) {
            int row = row0 + quad * 4 + r;
            if (row < M) {
                float v = scrub(acc[t][r] + bv);
                if (cf) ((float*)cp)[(size_t)row * 128 + colx] = v;
                else ((unsigned short*)cp)[(size_t)row * 128 + colx] = f2bf(v);
            }
        }
    }
}

// generic-K fallback (runtime loop, round-3 structure); only used if K not in {128,256}
__device__ __forceinline__ short8 load_frag(const void* A, size_t row, int K, int off, int f32m) {
    if (!f32m)
        return *(const short8*)((const unsigned short*)A + row * (size_t)K + off);
    const float* p = (const float*)A + row * (size_t)K + off;
    short8 r;
#pragma unroll
    for (int j = 0; j < 8; ++j) r[j] = (short)f2bf(p[j]);
    return r;
}

__global__ __launch_bounds__(256) void k_gemm_gen(
    const void* __restrict__ A, const short8* __restrict__ Wf,
    void* __restrict__ Cbase, const void* __restrict__ bias,
    int M, int K, const int* __restrict__ flags,
    int a_ext, int c_half, int c_ext) {
    int xf = flags[1];
    int af = a_ext & xf;
    int cf = c_ext & xf;
    char* cp = (char*)Cbase + (size_t)c_half * (size_t)M * 128 * (xf ? 4 : 2);
    int tid = threadIdx.x;
    int wave = tid >> 6, lane = tid & 63;
    int quad = lane >> 4, l16 = lane & 15;
    int row0 = (blockIdx.x * 4 + wave) * 16;
    if (row0 >= M) return;
    size_t ar = (size_t)min(row0 + l16, M - 1);
    f32x4 acc[8];
#pragma unroll
    for (int t = 0; t < 8; ++t) acc[t] = (f32x4){0.f, 0.f, 0.f, 0.f};
    int nks = K >> 5;
    for (int ksg = 0; ksg < nks; ++ksg) {
        short8 a = load_frag(A, ar, K, (ksg << 5) + quad * 8, af);
        const short8* wrow = Wf + (size_t)(ksg << 3) * 64 + lane;
#pragma unroll
        for (int t = 0; t < 8; ++t)
            acc[t] = __builtin_amdgcn_mfma_f32_16x16x32_bf16(a, wrow[t * 64], acc[t], 0, 0, 0);
    }
#pragma unroll
    for (int t = 0; t < 8; ++t) {
        int colx = t * 16 + l16;
        float bv = bias ? ldext(bias, colx, xf) : 0.f;
#pragma unroll
        for (int r = 0; r < 4; ++r) {
            int row = row0 + quad * 4 + r;
            if (row < M) {
                float v = scrub(acc[t][r] + bv);
                if (cf) ((float*)cp)[(size_t)row * 128 + colx] = v;
                else ((unsigned short*)cp)[(size_t)row * 128 + colx] = f2bf(v);
            }
        }
    }
}

// ---------------- aggregation: 16-lane group per node, 8 features/lane ----------------
// z[v] = sum_{u in N(v) U {v}} h[u]*dinv[u]*dinv[v] + b ; h always internal bf16.
// 1-deep software pipeline on (u, dinv[u], h[u]).

__global__ __launch_bounds__(256) void k_agg(
    const void* __restrict__ hbase, int h_half,
    const int* __restrict__ rowptr, const int* __restrict__ csr_src,
    const float* __restrict__ dinv, const void* __restrict__ bias,
    void* __restrict__ z, int z_ext,
    int n, int etot, const int* __restrict__ flags) {
    int v = (blockIdx.x * 256 + threadIdx.x) >> 4;   // group id = node
    if (v >= n) return;
    int xf = flags[1];
    int zf = z_ext & xf;
    const unsigned short* h = (const unsigned short*)
        ((const char*)hbase + (size_t)h_half * (size_t)n * 128 * (xf ? 4 : 2));
    int g = threadIdx.x & 15;                         // lane-in-group, 8 feats
    float di = dinv[v];
    int s = rowptr[v], e = rowptr[v + 1];
    if (e > etot) e = etot;
    if (s < 0) s = 0;

    short8 hv = *(const short8*)(h + (size_t)v * 128 + g * 8);
    float sw = di * di;
    float acc[8];
#pragma unroll
    for (int j = 0; j < 8; ++j) acc[j] = bf2f((unsigned short)hv[j]) * sw;

    // pipelined neighbor loop
    int u0 = (s < e) ? csr_src[s] : 0;
    if ((unsigned)u0 >= (unsigned)n) u0 = 0;
    float du0 = dinv[u0];
    short8 h0 = *(const short8*)(h + (size_t)u0 * 128 + g * 8);
    for (int i = s; i < e; ++i) {
        int u1 = (i + 1 < e) ? csr_src[i + 1] : 0;
        if ((unsigned)u1 >= (unsigned)n) u1 = 0;
        float du1 = dinv[u1];
        short8 h1 = *(const short8*)(h + (size_t)u1 * 128 + g * 8);
        float w = di * du0;
#pragma unroll
        for (int j = 0; j < 8; ++j) acc[j] += bf2f((unsigned short)h0[j]) * w;
        u0 = u1; du0 = du1; h0 = h1;
    }

#pragma unroll
    for (int j = 0; j < 8; ++j)
        acc[j] = scrub(acc[j] + ldext(bias, g * 8 + j, xf));

    if (zf) {
        float* zp = (float*)z + (size_t)v * 128 + g * 8;
        f32x4 o0 = {acc[0], acc[1], acc[2], acc[3]};
        f32x4 o1 = {acc[4], acc[5], acc[6], acc[7]};
        *(f32x4*)zp = o0;
        *(f32x4*)(zp + 4) = o1;
    } else {
        short8 o;
#pragma unroll
        for (int j = 0; j < 8; ++j) o[j] = (short)f2bf(acc[j]);
        *(short8*)((unsigned short*)z + (size_t)v * 128 + g * 8) = o;
    }
}

// ---------------- launch ----------------

static inline size_t alignup(size_t x) { return (x + 255) & ~(size_t)255; }

extern "C" void kernel_launch(void* const* d_in, const int* in_sizes, int n_in,
                              void* d_out, int out_size, void* d_ws, size_t ws_size,
                              hipStream_t stream) {
    const void* x  = d_in[0];
    const int*  ei = (const int*)d_in[1];
    const void* W1 = d_in[2];
    const void* b1 = d_in[3];
    const void* W2 = d_in[4];
    const void* b2 = d_in[5];
    const void* Wp = d_in[6];
    const void* bp = d_in[7];

    const int HID = in_sizes[3];            // 128
    const int IN_DIM = in_sizes[2] / HID;   // 256
    const int N = in_sizes[0] / IN_DIM;     // 100000
    const int E = in_sizes[1] / 2;          // 1600000

    // workspace layout
    char* w = (char*)d_ws;
    int* flags = (int*)w;      w += 256;
    int* rowptr = (int*)w;     w += alignup(sizeof(int) * (size_t)(N + 1));
    float* dinv = (float*)w;   w += alignup(sizeof(float) * (size_t)N);
    int* bcnt = (int*)w;       w += 4096;
    int* boff = (int*)w;       w += 8192;
    int* bcur = (int*)w;       w += 4096;
    short8* wf1 = (short8*)w;  w += alignup((size_t)IN_DIM * HID * 2);
    short8* wf2 = (short8*)w;  w += alignup((size_t)HID * HID * 2);
    short8* wfp = (short8*)w;  w += alignup((size_t)HID * HID * 2);
    int* csr_src = (int*)w;    w += alignup(sizeof(int) * (size_t)E);
    size_t fixed = (size_t)(w - (char*)d_ws);
    size_t bufbytes = alignup((size_t)N * HID * 2);
    bool wsmode = ws_size >= fixed + 2 * bufbytes;

    // binned edge records live in d_out scratch (dead until layer-2 agg writes)
    int* binned = (int*)d_out;

    void* hC;  int h_half;
    void* z1p;
    if (wsmode) {
        hC = (void*)w;  h_half = 0;
        z1p = (void*)(w + bufbytes);
    } else {
        hC = d_out;     h_half = 1;
        z1p = d_out;
    }

    int nb = (N + BNODES - 1) >> BSH;       // buckets (98 for N=100k); needs nb<=1024
    int ebb = (E + 256 * EPB - 1) / (256 * EPB);
    int gemm_blocks = (N + 63) / 64;        // 4 waves/block, 16 rows/wave
    int agg_blocks = (N + 15) / 16;

    auto launch_gemm = [&](const void* A, const short8* Wf, void* C, const void* bias,
                           int K, int aext, int chalf, int cext) {
        if (K == 256) {
            if (aext) k_gemmT<8, 1><<<gemm_blocks, 256, 0, stream>>>(A, Wf, C, bias, N, flags, chalf, cext);
            else      k_gemmT<8, 0><<<gemm_blocks, 256, 0, stream>>>(A, Wf, C, bias, N, flags, chalf, cext);
        } else if (K == 128) {
            if (aext) k_gemmT<4, 1><<<gemm_blocks, 256, 0, stream>>>(A, Wf, C, bias, N, flags, chalf, cext);
            else      k_gemmT<4, 0><<<gemm_blocks, 256, 0, stream>>>(A, Wf, C, bias, N, flags, chalf, cext);
        } else {
            k_gemm_gen<<<gemm_blocks, 256, 0, stream>>>(A, Wf, C, bias, N, K, flags, aext, chalf, cext);
        }
    };

    // probes + weight prep + bucketed CSR build
    k_detect<<<1, 64, 0, stream>>>(ei, (const unsigned short*)x, flags);
    k_wprep<<<(IN_DIM * 16 + 255) / 256, 256, 0, stream>>>(W1, wf1, IN_DIM, flags);
    k_wprep<<<(HID * 16 + 255) / 256, 256, 0, stream>>>(W2, wf2, HID, flags);
    k_wprep<<<(HID * 16 + 255) / 256, 256, 0, stream>>>(Wp, wfp, HID, flags);
    k_zero<<<(nb + 255) / 256, 256, 0, stream>>>(bcnt, nb);
    k_bcount<<<ebb, 256, 0, stream>>>(ei, flags, bcnt, E, N, nb);
    k_bscan<<<1, 1024, 0, stream>>>(bcnt, boff, bcur, nb, E, rowptr, N);
    k_bin<<<ebb, 256, 0, stream>>>(ei, flags, bcur, binned, E, N, nb);
    k_build<<<nb, 256, 0, stream>>>(binned, boff, rowptr, dinv, csr_src, N);

    // layer 1: h1 = x@W1 (bf16 scratch); z1 = agg(h1)+b1 (bf16 scratch)
    launch_gemm(x, wf1, hC, nullptr, IN_DIM, 1, h_half, 0);
    k_agg<<<agg_blocks, 256, 0, stream>>>(hC, h_half, rowptr, csr_src, dinv, b1,
                                          z1p, 0, N, E, flags);

    // layer 2: h2 = z1@W2 (bf16 scratch); z2 = agg(h2)+b2 -> d_out half 0 (final fmt)
    launch_gemm(z1p, wf2, hC, nullptr, HID, 0, h_half, 0);
    k_agg<<<agg_blocks, 256, 0, stream>>>(hC, h_half, rowptr, csr_src, dinv, b2,
                                          d_out, 1, N, E, flags);

    // proj = z2@Wp + bp -> d_out half 1 (final fmt)
    launch_gemm(d_out, wfp, d_out, bp, HID, 1, 1, 1);
}

// Round 5
// 500.980 us; speedup vs baseline: 1.1327x; 1.0236x over previous
//
#include <hip/hip_runtime.h>

typedef __attribute__((ext_vector_type(8))) short short8;
typedef __attribute__((ext_vector_type(4))) float f32x4;

__device__ __forceinline__ float bf2f(unsigned short u) {
    union { unsigned int i; float f; } v; v.i = ((unsigned int)u) << 16; return v.f;
}
__device__ __forceinline__ unsigned short f2bf(float f) {
    union { float f; unsigned int i; } v; v.f = f;
    unsigned int i = v.i;
    return (unsigned short)((i + 0x7FFFu + ((i >> 16) & 1u)) >> 16);  // RNE
}
__device__ __forceinline__ float ldext(const void* p, size_t i, int xf) {
    return xf ? ((const float*)p)[i] : bf2f(((const unsigned short*)p)[i]);
}
__device__ __forceinline__ float scrub(float v) {
    return (__builtin_fabsf(v) < 1e30f) ? v : 9.0f;
}
__device__ __forceinline__ short8 as_short8(f32x4 v) {
    union { f32x4 f; short8 s; } u; u.f = v; return u.s;
}
__device__ __forceinline__ f32x4 as_f32x4(short8 v) {
    union { short8 s; f32x4 f; } u; u.s = v; return u.f;
}

// ---------------- dtype probes (one wave) ----------------
// flags[0]: 1 => edge_index is int64 words; flags[1]: 1 => floats are f32
__global__ void k_detect(const int* __restrict__ ei, const unsigned short* __restrict__ xs,
                         int* __restrict__ flags) {
    int lane = threadIdx.x;  // 64 threads, 1 block
    int orv = 0;
    for (int i = 2 * lane + 1; i < 256; i += 128) orv |= ei[i];
    int cnt = 0;
    for (int i = lane; i < 256; i += 64) {
        int e = (xs[i] >> 7) & 0xFF;
        cnt += (e >= 97 && e <= 159) ? 1 : 0;
    }
    for (int off = 32; off > 0; off >>= 1) {
        orv |= __shfl_down(orv, off);
        cnt += __shfl_down(cnt, off);
    }
    if (lane == 0) {
        flags[0] = (orv == 0) ? 1 : 0;
        flags[1] = (cnt >= 240) ? 0 : 1;
    }
}

// ---------------- bucketed CSR build ----------------
// Buckets of BNODES=1024 consecutive nodes. Records pack (c_local<<22 | r):
// valid while N <= 2^22 and nb <= 1024 (i.e. N <= 2^20 for LDS hist).
#define BSH 10
#define BNODES (1 << BSH)
#define RBITS (32 - BSH)
#define EPB 16  // edges per thread in the binning kernels

__global__ void k_zero(int* __restrict__ p, int n) {
    int i = blockIdx.x * 256 + threadIdx.x;
    if (i < n) p[i] = 0;
}

// pass 0: per-bucket edge counts (LDS histogram, ~nb global atomics per block)
__global__ __launch_bounds__(256) void k_bcount(const int* __restrict__ ei,
                                                const int* __restrict__ flags,
                                                int* __restrict__ bcnt,
                                                int e, int n, int nb) {
    __shared__ int hist[1024];
    int tid = threadIdx.x;
    for (int i = tid; i < 1024; i += 256) hist[i] = 0;
    __syncthreads();
    int f = flags[0];
    long base = (long)blockIdx.x * (256 * EPB);
#pragma unroll
    for (int j = 0; j < EPB; ++j) {
        long i = base + j * 256 + tid;
        if (i < e) {
            int c = ei[(e + i) << f];
            if ((unsigned)c >= (unsigned)n) c = 0;
            atomicAdd(&hist[c >> BSH], 1);
        }
    }
    __syncthreads();
    for (int b = tid; b < nb; b += 256) {
        int h = hist[b];
        if (h) atomicAdd(&bcnt[b], h);
    }
}

// single block: exclusive scan of bucket counts -> boff, bcur; rowptr[n]=e
__global__ __launch_bounds__(1024) void k_bscan(const int* __restrict__ bcnt,
                                                int* __restrict__ boff,
                                                int* __restrict__ bcur,
                                                int nb, int e,
                                                int* __restrict__ rowptr, int n) {
    __shared__ int ws[16];
    int t = threadIdx.x, lane = t & 63, wv = t >> 6;
    int v = (t < nb) ? bcnt[t] : 0;
    int s = v;
    for (int off = 1; off < 64; off <<= 1) {
        int x = __shfl_up(s, off);
        if (lane >= off) s += x;
    }
    if (lane == 63) ws[wv] = s;
    __syncthreads();
    if (wv == 0 && lane < 16) {
        int w = ws[lane];
        for (int off = 1; off < 16; off <<= 1) {
            int x = __shfl_up(w, off);
            if (lane >= off) w += x;
        }
        ws[lane] = w;
    }
    __syncthreads();
    int excl = (wv ? ws[wv - 1] : 0) + s - v;
    if (t < nb) { boff[t] = excl; bcur[t] = excl; }
    if (t == 0) { boff[nb] = e; rowptr[n] = e; }
}

// pass A: bin edges into bucket regions as packed records (contiguous runs/block)
__global__ __launch_bounds__(256) void k_bin(const int* __restrict__ ei,
                                             const int* __restrict__ flags,
                                             int* __restrict__ bcur,
                                             int* __restrict__ binned,
                                             int e, int n, int nb) {
    __shared__ int hist[1024];
    __shared__ int wbase[1024];
    int tid = threadIdx.x;
    for (int i = tid; i < 1024; i += 256) hist[i] = 0;
    __syncthreads();
    int f = flags[0];
    long base = (long)blockIdx.x * (256 * EPB);
    int cs[EPB], rr[EPB];
#pragma unroll
    for (int j = 0; j < EPB; ++j) {
        long i = base + j * 256 + tid;
        int c = -1, r = 0;
        if (i < e) {
            c = ei[(e + i) << f];
            r = ei[i << f];
            if ((unsigned)c >= (unsigned)n) c = 0;
            if ((unsigned)r >= (unsigned)n) r = 0;
            atomicAdd(&hist[c >> BSH], 1);
        }
        cs[j] = c;
        rr[j] = r;
    }
    __syncthreads();
    for (int b = tid; b < nb; b += 256) {
        int h = hist[b];
        wbase[b] = h ? atomicAdd(&bcur[b], h) : 0;
    }
    __syncthreads();
    for (int i = tid; i < 1024; i += 256) hist[i] = 0;  // reuse as intra-block cursor
    __syncthreads();
#pragma unroll
    for (int j = 0; j < EPB; ++j) {
        int c = cs[j];
        if (c >= 0) {
            int b = c >> BSH;
            int off = atomicAdd(&hist[b], 1);
            int rec = rr[j] | ((c & (BNODES - 1)) << RBITS);
            binned[wbase[b] + off] = rec;
        }
    }
}

// pass B: one block per bucket. LDS node-histogram -> rowptr/dinv/cursors,
// then LDS-atomic scatter into the bucket's L2-resident csr_src region.
__global__ __launch_bounds__(256) void k_build(const int* __restrict__ binned,
                                               const int* __restrict__ boff,
                                               int* __restrict__ rowptr,
                                               float* __restrict__ dinv,
                                               int* __restrict__ csr_src,
                                               int n) {
    __shared__ int hist[1024];
    __shared__ int ws4[4];
    int b = blockIdx.x;
    int tid = threadIdx.x;
    int v0 = b << BSH;
    int rs = boff[b], re = boff[b + 1];
    for (int i = tid; i < 1024; i += 256) hist[i] = 0;
    __syncthreads();
    for (int i = rs + tid; i < re; i += 256)
        atomicAdd(&hist[((unsigned)binned[i]) >> RBITS], 1);
    __syncthreads();
    // in-place exclusive scan of hist[0..1023]; thread owns 4 consecutive slots
    int idx = tid * 4;
    int h0 = hist[idx], h1 = hist[idx + 1], h2 = hist[idx + 2], h3 = hist[idx + 3];
    int ls = h0 + h1 + h2 + h3;
    int lane = tid & 63, wv = tid >> 6;
    int s = ls;
    for (int off = 1; off < 64; off <<= 1) {
        int x = __shfl_up(s, off);
        if (lane >= off) s += x;
    }
    if (lane == 63) ws4[wv] = s;
    __syncthreads();
    int wb = 0;
    for (int k = 0; k < 4; ++k) wb += (k < wv) ? ws4[k] : 0;
    int excl = wb + (s - ls);
    int e0 = excl, e1 = excl + h0, e2 = e1 + h1, e3 = e2 + h2;
    hist[idx] = rs + e0; hist[idx + 1] = rs + e1;
    hist[idx + 2] = rs + e2; hist[idx + 3] = rs + e3;
    int vv = v0 + idx;
    if (vv < n)     { rowptr[vv]     = rs + e0; dinv[vv]     = rsqrtf((float)(h0 + 1)); }
    if (vv + 1 < n) { rowptr[vv + 1] = rs + e1; dinv[vv + 1] = rsqrtf((float)(h1 + 1)); }
    if (vv + 2 < n) { rowptr[vv + 2] = rs + e2; dinv[vv + 2] = rsqrtf((float)(h2 + 1)); }
    if (vv + 3 < n) { rowptr[vv + 3] = rs + e3; dinv[vv + 3] = rsqrtf((float)(h3 + 1)); }
    __syncthreads();
    for (int i = rs + tid; i < re; i += 256) {
        int rec = binned[i];
        int cl = ((unsigned)rec) >> RBITS;
        int r = rec & ((1 << RBITS) - 1);
        int pos = atomicAdd(&hist[cl], 1);
        csr_src[pos] = r;
    }
}

// ---------------- MFMA GEMM: C[M,128] = A[M,K] @ W[K,128] (+bias) ----------------
// LDS-free, barrier-free, latency-tolerant: one wave owns 16 rows; the ENTIRE
// A K-panel (NKS frags) is prefetched before the MFMA loop (16KB in flight/wave
// for f32 K=256), W fragments stream from L2 with a register double-buffer.

// Wf layout: frag row f = ksg*8 + t (ksg = k/32); lane l holds short8 with
// elem j = W[ksg*32 + (l>>4)*8 + j][t*16 + (l&15)]  -> Wf[f*64 + l]
__global__ __launch_bounds__(256) void k_wprep(const void* __restrict__ W,
                                               short8* __restrict__ Wf,
                                               int K, const int* __restrict__ flags) {
    int idx = blockIdx.x * 256 + threadIdx.x;   // = f*64 + lane
    int total = (K >> 5) * 8 * 64;
    if (idx >= total) return;
    int lane = idx & 63, frow = idx >> 6;
    int t = frow & 7, ksg = frow >> 3;
    int col = t * 16 + (lane & 15);
    int k0 = ksg * 32 + ((lane >> 4) << 3);
    int xf = flags[1];
    short8 val;
    if (xf) {
        const float* wp = (const float*)W + (size_t)k0 * 128 + col;
#pragma unroll
        for (int j = 0; j < 8; ++j) val[j] = (short)f2bf(wp[(size_t)j * 128]);
    } else {
        const unsigned short* wp = (const unsigned short*)W + (size_t)k0 * 128 + col;
#pragma unroll
        for (int j = 0; j < 8; ++j) val[j] = (short)wp[(size_t)j * 128];
    }
    Wf[idx] = val;
}

__device__ __forceinline__ void loadw(short8 (&w)[8], const short8* __restrict__ Wf,
                                      int ksg, int lane) {
#pragma unroll
    for (int t = 0; t < 8; ++t) w[t] = Wf[(size_t)((ksg << 3) + t) * 64 + lane];
}

template<int AEXT>
__device__ __forceinline__ short8 cvt_frag(short8 lo, short8 hi, int af) {
    if (AEXT == 0) return lo;
    if (!af) return lo;
    f32x4 f0 = as_f32x4(lo), f1 = as_f32x4(hi);
    short8 r;
#pragma unroll
    for (int j = 0; j < 4; ++j) {
        r[j] = (short)f2bf(f0[j]);
        r[j + 4] = (short)f2bf(f1[j]);
    }
    return r;
}

__device__ __forceinline__ void step8(f32x4 (&acc)[8], short8 a, short8 (&w)[8]) {
#pragma unroll
    for (int t = 0; t < 8; ++t)
        acc[t] = __builtin_amdgcn_mfma_f32_16x16x32_bf16(a, w[t], acc[t], 0, 0, 0);
}

template<int NKS, int AEXT>
__global__ __launch_bounds__(256) void k_gemmT(
    const void* __restrict__ A, const short8* __restrict__ Wf,
    void* __restrict__ Cbase, const void* __restrict__ bias,
    int M, const int* __restrict__ flags, int c_half, int c_ext) {
    const int K = NKS * 32;
    int xf = flags[1];
    int af = AEXT & xf;
    int cf = c_ext & xf;
    char* cp = (char*)Cbase + (size_t)c_half * (size_t)M * 128 * (xf ? 4 : 2);

    int tid = threadIdx.x;
    int wave = tid >> 6, lane = tid & 63;
    int quad = lane >> 4, l16 = lane & 15;
    int row0 = (blockIdx.x * 4 + wave) * 16;    // wave-private 16-row tile
    if (row0 >= M) return;
    size_t ar = (size_t)min(row0 + l16, M - 1);

    // prefetch the whole A K-panel (all loads in flight before first MFMA)
    short8 a_lo[NKS], a_hi[NKS];
#pragma unroll
    for (int k = 0; k < NKS; ++k) {
        if (AEXT && af) {
            const f32x4* p = (const f32x4*)((const float*)A + ar * (size_t)K + k * 32 + quad * 8);
            a_lo[k] = as_short8(p[0]);
            a_hi[k] = as_short8(p[1]);
        } else {
            a_lo[k] = *(const short8*)((const unsigned short*)A + ar * (size_t)K + k * 32 + quad * 8);
        }
    }

    f32x4 acc[8];
#pragma unroll
    for (int t = 0; t < 8; ++t) acc[t] = (f32x4){0.f, 0.f, 0.f, 0.f};

    short8 wA[8], wB[8];
    loadw(wA, Wf, 0, lane);
#pragma unroll
    for (int kp = 0; kp < NKS; kp += 2) {
        if (kp + 1 < NKS) loadw(wB, Wf, kp + 1, lane);
        step8(acc, cvt_frag<AEXT>(a_lo[kp], a_hi[kp], af), wA);
        if (kp + 2 < NKS) loadw(wA, Wf, kp + 2, lane);
        if (kp + 1 < NKS) step8(acc, cvt_frag<AEXT>(a_lo[kp + 1], a_hi[kp + 1], af), wB);
    }

#pragma unroll
    for (int t = 0; t < 8; ++t) {
        int colx = t * 16 + l16;
        float bv = bias ? ldext(bias, colx, xf) : 0.f;
#pragma unroll
        for (int r = 0; r < 4; ++r) {
            int row = row0 + quad * 4 + r;
            if (row < M) {
                float v = scrub(acc[t][r] + bv);
                if (cf) ((float*)cp)[(size_t)row * 128 + colx] = v;
                else ((unsigned short*)cp)[(size_t)row * 128 + colx] = f2bf(v);
            }
        }
    }
}

// generic-K fallback (runtime loop); only used if K not in {128,256}
__device__ __forceinline__ short8 load_frag(const void* A, size_t row, int K, int off, int f32m) {
    if (!f32m)
        return *(const short8*)((const unsigned short*)A + row * (size_t)K + off);
    const float* p = (const float*)A + row * (size_t)K + off;
    short8 r;
#pragma unroll
    for (int j = 0; j < 8; ++j) r[j] = (short)f2bf(p[j]);
    return r;
}

__global__ __launch_bounds__(256) void k_gemm_gen(
    const void* __restrict__ A, const short8* __restrict__ Wf,
    void* __restrict__ Cbase, const void* __restrict__ bias,
    int M, int K, const int* __restrict__ flags,
    int a_ext, int c_half, int c_ext) {
    int xf = flags[1];
    int af = a_ext & xf;
    int cf = c_ext & xf;
    char* cp = (char*)Cbase + (size_t)c_half * (size_t)M * 128 * (xf ? 4 : 2);
    int tid = threadIdx.x;
    int wave = tid >> 6, lane = tid & 63;
    int quad = lane >> 4, l16 = lane & 15;
    int row0 = (blockIdx.x * 4 + wave) * 16;
    if (row0 >= M) return;
    size_t ar = (size_t)min(row0 + l16, M - 1);
    f32x4 acc[8];
#pragma unroll
    for (int t = 0; t < 8; ++t) acc[t] = (f32x4){0.f, 0.f, 0.f, 0.f};
    int nks = K >> 5;
    for (int ksg = 0; ksg < nks; ++ksg) {
        short8 a = load_frag(A, ar, K, (ksg << 5) + quad * 8, af);
        const short8* wrow = Wf + (size_t)(ksg << 3) * 64 + lane;
#pragma unroll
        for (int t = 0; t < 8; ++t)
            acc[t] = __builtin_amdgcn_mfma_f32_16x16x32_bf16(a, wrow[t * 64], acc[t], 0, 0, 0);
    }
#pragma unroll
    for (int t = 0; t < 8; ++t) {
        int colx = t * 16 + l16;
        float bv = bias ? ldext(bias, colx, xf) : 0.f;
#pragma unroll
        for (int r = 0; r < 4; ++r) {
            int row = row0 + quad * 4 + r;
            if (row < M) {
                float v = scrub(acc[t][r] + bv);
                if (cf) ((float*)cp)[(size_t)row * 128 + colx] = v;
                else ((unsigned short*)cp)[(size_t)row * 128 + colx] = f2bf(v);
            }
        }
    }
}

// ---------------- aggregation: one WAVE per node ----------------
// 4 subgroups of 16 lanes; subgroup sg handles neighbors i = s+sg, s+sg+4, ...
// Each lane owns 8 features (16B). 1-ahead pipeline per subgroup -> up to 8
// independent 256B gathers in flight per wave (4x the serial-group version).
// Combine subgroup partials with shfl_xor(16/32); sg0 adds self term + writes.

__global__ __launch_bounds__(256) void k_agg(
    const void* __restrict__ hbase, int h_half,
    const int* __restrict__ rowptr, const int* __restrict__ csr_src,
    const float* __restrict__ dinv, const void* __restrict__ bias,
    void* __restrict__ z, int z_ext,
    int n, int etot, const int* __restrict__ flags) {
    int wave = threadIdx.x >> 6;
    int v = blockIdx.x * 4 + wave;
    if (v >= n) return;
    int xf = flags[1];
    int zf = z_ext & xf;
    const unsigned short* h = (const unsigned short*)
        ((const char*)hbase + (size_t)h_half * (size_t)n * 128 * (xf ? 4 : 2));
    int lane = threadIdx.x & 63;
    int sg = lane >> 4;                    // subgroup 0..3
    int g = lane & 15;                     // feature slot, 8 feats each
    float di = dinv[v];
    int s = rowptr[v], e = rowptr[v + 1];
    if (e > etot) e = etot;
    if (s < 0) s = 0;

    float acc[8];
    if (sg == 0) {
        short8 hv = *(const short8*)(h + (size_t)v * 128 + g * 8);
        float sw = di * di;
#pragma unroll
        for (int j = 0; j < 8; ++j) acc[j] = bf2f((unsigned short)hv[j]) * sw;
    } else {
#pragma unroll
        for (int j = 0; j < 8; ++j) acc[j] = 0.f;
    }

    // pipelined strided neighbor loop (stride 4 across subgroups)
    int i0 = s + sg;
    int u0 = (i0 < e) ? csr_src[i0] : 0;
    if ((unsigned)u0 >= (unsigned)n) u0 = 0;
    float du0 = dinv[u0];
    short8 h0 = *(const short8*)(h + (size_t)u0 * 128 + g * 8);
    for (int i = i0; i < e; i += 4) {
        int i1 = i + 4;
        int u1 = (i1 < e) ? csr_src[i1] : 0;
        if ((unsigned)u1 >= (unsigned)n) u1 = 0;
        float du1 = dinv[u1];
        short8 h1 = *(const short8*)(h + (size_t)u1 * 128 + g * 8);
        float w = di * du0;
#pragma unroll
        for (int j = 0; j < 8; ++j) acc[j] += bf2f((unsigned short)h0[j]) * w;
        u0 = u1; du0 = du1; h0 = h1;
    }

    // combine subgroup partials (lanes with equal g across sg 0..3)
#pragma unroll
    for (int j = 0; j < 8; ++j) {
        acc[j] += __shfl_xor(acc[j], 16);
        acc[j] += __shfl_xor(acc[j], 32);
    }

    if (sg == 0) {
#pragma unroll
        for (int j = 0; j < 8; ++j)
            acc[j] = scrub(acc[j] + ldext(bias, g * 8 + j, xf));
        if (zf) {
            float* zp = (float*)z + (size_t)v * 128 + g * 8;
            f32x4 o0 = {acc[0], acc[1], acc[2], acc[3]};
            f32x4 o1 = {acc[4], acc[5], acc[6], acc[7]};
            *(f32x4*)zp = o0;
            *(f32x4*)(zp + 4) = o1;
        } else {
            short8 o;
#pragma unroll
            for (int j = 0; j < 8; ++j) o[j] = (short)f2bf(acc[j]);
            *(short8*)((unsigned short*)z + (size_t)v * 128 + g * 8) = o;
        }
    }
}

// ---------------- launch ----------------

static inline size_t alignup(size_t x) { return (x + 255) & ~(size_t)255; }

extern "C" void kernel_launch(void* const* d_in, const int* in_sizes, int n_in,
                              void* d_out, int out_size, void* d_ws, size_t ws_size,
                              hipStream_t stream) {
    const void* x  = d_in[0];
    const int*  ei = (const int*)d_in[1];
    const void* W1 = d_in[2];
    const void* b1 = d_in[3];
    const void* W2 = d_in[4];
    const void* b2 = d_in[5];
    const void* Wp = d_in[6];
    const void* bp = d_in[7];

    const int HID = in_sizes[3];            // 128
    const int IN_DIM = in_sizes[2] / HID;   // 256
    const int N = in_sizes[0] / IN_DIM;     // 100000
    const int E = in_sizes[1] / 2;          // 1600000

    // workspace layout
    char* w = (char*)d_ws;
    int* flags = (int*)w;      w += 256;
    int* rowptr = (int*)w;     w += alignup(sizeof(int) * (size_t)(N + 1));
    float* dinv = (float*)w;   w += alignup(sizeof(float) * (size_t)N);
    int* bcnt = (int*)w;       w += 4096;
    int* boff = (int*)w;       w += 8192;
    int* bcur = (int*)w;       w += 4096;
    short8* wf1 = (short8*)w;  w += alignup((size_t)IN_DIM * HID * 2);
    short8* wf2 = (short8*)w;  w += alignup((size_t)HID * HID * 2);
    short8* wfp = (short8*)w;  w += alignup((size_t)HID * HID * 2);
    int* csr_src = (int*)w;    w += alignup(sizeof(int) * (size_t)E);
    size_t fixed = (size_t)(w - (char*)d_ws);
    size_t bufbytes = alignup((size_t)N * HID * 2);
    bool wsmode = ws_size >= fixed + 2 * bufbytes;

    // binned edge records live in d_out scratch (dead until layer-2 agg writes)
    int* binned = (int*)d_out;

    void* hC;  int h_half;
    void* z1p;
    if (wsmode) {
        hC = (void*)w;  h_half = 0;
        z1p = (void*)(w + bufbytes);
    } else {
        hC = d_out;     h_half = 1;
        z1p = d_out;
    }

    int nb = (N + BNODES - 1) >> BSH;       // buckets (98 for N=100k); needs nb<=1024
    int ebb = (E + 256 * EPB - 1) / (256 * EPB);
    int gemm_blocks = (N + 63) / 64;        // 4 waves/block, 16 rows/wave
    int agg_blocks = (N + 3) / 4;           // 4 waves/block, 1 node/wave

    auto launch_gemm = [&](const void* A, const short8* Wf, void* C, const void* bias,
                           int K, int aext, int chalf, int cext) {
        if (K == 256) {
            if (aext) k_gemmT<8, 1><<<gemm_blocks, 256, 0, stream>>>(A, Wf, C, bias, N, flags, chalf, cext);
            else      k_gemmT<8, 0><<<gemm_blocks, 256, 0, stream>>>(A, Wf, C, bias, N, flags, chalf, cext);
        } else if (K == 128) {
            if (aext) k_gemmT<4, 1><<<gemm_blocks, 256, 0, stream>>>(A, Wf, C, bias, N, flags, chalf, cext);
            else      k_gemmT<4, 0><<<gemm_blocks, 256, 0, stream>>>(A, Wf, C, bias, N, flags, chalf, cext);
        } else {
            k_gemm_gen<<<gemm_blocks, 256, 0, stream>>>(A, Wf, C, bias, N, K, flags, aext, chalf, cext);
        }
    };

    // probes + weight prep + bucketed CSR build
    k_detect<<<1, 64, 0, stream>>>(ei, (const unsigned short*)x, flags);
    k_wprep<<<(IN_DIM * 16 + 255) / 256, 256, 0, stream>>>(W1, wf1, IN_DIM, flags);
    k_wprep<<<(HID * 16 + 255) / 256, 256, 0, stream>>>(W2, wf2, HID, flags);
    k_wprep<<<(HID * 16 + 255) / 256, 256, 0, stream>>>(Wp, wfp, HID, flags);
    k_zero<<<(nb + 255) / 256, 256, 0, stream>>>(bcnt, nb);
    k_bcount<<<ebb, 256, 0, stream>>>(ei, flags, bcnt, E, N, nb);
    k_bscan<<<1, 1024, 0, stream>>>(bcnt, boff, bcur, nb, E, rowptr, N);
    k_bin<<<ebb, 256, 0, stream>>>(ei, flags, bcur, binned, E, N, nb);
    k_build<<<nb, 256, 0, stream>>>(binned, boff, rowptr, dinv, csr_src, N);

    // layer 1: h1 = x@W1 (bf16 scratch); z1 = agg(h1)+b1 (bf16 scratch)
    launch_gemm(x, wf1, hC, nullptr, IN_DIM, 1, h_half, 0);
    k_agg<<<agg_blocks, 256, 0, stream>>>(hC, h_half, rowptr, csr_src, dinv, b1,
                                          z1p, 0, N, E, flags);

    // layer 2: h2 = z1@W2 (bf16 scratch); z2 = agg(h2)+b2 -> d_out half 0 (final fmt)
    launch_gemm(z1p, wf2, hC, nullptr, HID, 0, h_half, 0);
    k_agg<<<agg_blocks, 256, 0, stream>>>(hC, h_half, rowptr, csr_src, dinv, b2,
                                          d_out, 1, N, E, flags);

    // proj = z2@Wp + bp -> d_out half 1 (final fmt)
    launch_gemm(d_out, wfp, d_out, bp, HID, 1, 1, 1);
}